// Round 2
// baseline (420.335 us; speedup 1.0000x reference)
//
#include <hip/hip_runtime.h>
#include <hip/hip_bf16.h>
#include <math.h>

// Problem constants
#define B_ 2
#define N_ 2048
#define E_ 1024
#define H_ 16
#define D_ 64
#define HALF_ 32
#define CK 64              // attention chunk size
#define NC (N_/CK)         // 32 chunks
#define BN (B_*N_)         // 4096 rows
#define LDP 76             // LDS row pad for fp32 tiles
#define EPS_ 1e-5f

using bf16x8 = __attribute__((ext_vector_type(8))) short;
using f32x4  = __attribute__((ext_vector_type(4))) float;
using s4     = __attribute__((ext_vector_type(4))) short;

__device__ __forceinline__ float sigmoid_(float v){ return 1.0f/(1.0f + __expf(-v)); }

// bf16 bit helpers (RNE), no NaN handling needed for this data
__device__ __forceinline__ unsigned short f2bf(float f){
  unsigned u = __float_as_uint(f);
  unsigned r = (u + 0x7fffu + ((u>>16)&1u)) >> 16;
  return (unsigned short)r;
}
__device__ __forceinline__ float bf2f(unsigned short h){
  return __uint_as_float(((unsigned)h)<<16);
}

#define GLDS16(gp, lp) __builtin_amdgcn_global_load_lds( \
    (const __attribute__((address_space(1))) void*)(gp), \
    (__attribute__((address_space(3))) void*)(lp), 16, 0, 0)

// ---------------- cos/sin table (fp32, matches jax fp32 path) ----------------
__global__ __launch_bounds__(256) void sincos_kernel(float* __restrict__ ct,
                                                     float* __restrict__ st){
  int i = blockIdx.x*256 + threadIdx.x;      // i < N_*HALF_
  int n = i >> 5, j = i & (HALF_-1);
  float invf = powf(10000.0f, -(float)(2*j)/(float)D_);
  float ang = (float)n * invf;
  ct[i] = cosf(ang);
  st[i] = sinf(ang);
}

// ---------------- split x (fp32) -> hi/lo bf16, same layout ----------------
__global__ __launch_bounds__(256) void xsplit_kernel(const float* __restrict__ x,
    short* __restrict__ xh, short* __restrict__ xl){
  int i = blockIdx.x*256 + threadIdx.x;   // float4 index
  float4 vv = ((const float4*)x)[i];
  float vs[4] = {vv.x, vv.y, vv.z, vv.w};
  s4 h, l;
  #pragma unroll
  for (int j=0;j<4;j++){
    unsigned short hb = f2bf(vs[j]);
    h[j] = (short)hb;
    l[j] = (short)f2bf(vs[j] - bf2f(hb));
  }
  ((s4*)xh)[i] = h;
  ((s4*)xl)[i] = l;
}

// ---------------- transpose + split W[K][N] -> Wt_hi/Wt_lo[N][K] (bf16) ----------------
__global__ __launch_bounds__(256) void wsplit_kernel(const float* __restrict__ W,
    short* __restrict__ Wth, short* __restrict__ Wtl, int K, int N){
  __shared__ float T[64][65];
  int k0 = blockIdx.x*64, n0 = blockIdx.y*64;
  int tid = threadIdx.x;
  #pragma unroll
  for (int it=0; it<4; ++it){
    int idx = it*256 + tid;            // 0..1023 float4 slots in 64x64 tile
    int r = idx >> 4, c = (idx & 15) << 2;
    float4 v = *(const float4*)&W[(size_t)(k0+r)*N + n0 + c];
    T[c+0][r]=v.x; T[c+1][r]=v.y; T[c+2][r]=v.z; T[c+3][r]=v.w;   // T[n][k]
  }
  __syncthreads();
  #pragma unroll
  for (int it=0; it<2; ++it){
    int idx = it*256 + tid;            // 0..511 groups of 8
    int r = idx >> 3, c8 = (idx & 7) << 3;   // r = n-row, c8 = k start
    bf16x8 h, l;
    #pragma unroll
    for (int j=0;j<8;j++){
      float v = T[r][c8+j];
      unsigned short hb = f2bf(v);
      h[j] = (short)hb;
      l[j] = (short)f2bf(v - bf2f(hb));
    }
    size_t o = (size_t)(n0+r)*K + k0 + c8;
    *(bf16x8*)&Wth[o] = h;
    *(bf16x8*)&Wtl[o] = l;
  }
}

// ---------------- MFMA split-bf16 GEMM: C[M][N] = A[M][K] @ W[K][N] ----------------
// A given as Ah/Al bf16 row-major [M][K]; W given as Bt hi/lo bf16 [N][K].
// BM=128, BN=64, BK=64, 256 threads (4 waves, 2x2), wave tile 64x32 (4x2 frags).
// LDS rows are 128 B; XOR-swizzle c ^= (row&7)<<4 on BOTH stage-source and read.
template<int EPI>
__global__ __launch_bounds__(256) void gemm_mfma(
    const short* __restrict__ Ah, const short* __restrict__ Al,
    const short* __restrict__ Bh, const short* __restrict__ Bl,
    float* __restrict__ C, int M, int N, int K)
{
  __shared__ __align__(16) short sAh[128*64];
  __shared__ __align__(16) short sAl[128*64];
  __shared__ __align__(16) short sBh[64*64];
  __shared__ __align__(16) short sBl[64*64];
  const int tid = threadIdx.x;
  const int l = tid & 63, w = tid >> 6;
  const int wm = w >> 1, wn = w & 1;
  const int m0 = blockIdx.x*128, n0 = blockIdx.y*64;
  const int Kb = K*2;                       // row stride in bytes
  f32x4 acc[4][2] = {};

  const char* gAh = (const char*)Ah;
  const char* gAl = (const char*)Al;
  const char* gBh = (const char*)Bh;
  const char* gBl = (const char*)Bl;

  const int nkt = K/64;
  for (int kt = 0; kt < nkt; ++kt){
    const int kbyte = kt*128;
    // stage A tiles (128 rows x 128 B): 4 calls each
    #pragma unroll
    for (int i=0;i<4;i++){
      int p   = i*4096 + tid*16;
      int row = p >> 7;
      int c   = (p & 127) ^ ((row & 7) << 4);
      size_t go = (size_t)(m0+row)*Kb + kbyte + c;
      char* lb  = (char*)sAh + i*4096 + w*1024;   // wave-uniform base
      char* lb2 = (char*)sAl + i*4096 + w*1024;
      GLDS16(gAh + go, lb);
      GLDS16(gAl + go, lb2);
    }
    // stage B tiles (64 rows x 128 B): 2 calls each
    #pragma unroll
    for (int i=0;i<2;i++){
      int p   = i*4096 + tid*16;
      int row = p >> 7;
      int c   = (p & 127) ^ ((row & 7) << 4);
      size_t go = (size_t)(n0+row)*Kb + kbyte + c;
      char* lb  = (char*)sBh + i*4096 + w*1024;
      char* lb2 = (char*)sBl + i*4096 + w*1024;
      GLDS16(gBh + go, lb);
      GLDS16(gBl + go, lb2);
    }
    __syncthreads();
    #pragma unroll
    for (int kb=0;kb<2;kb++){
      const int cb = kb*64 + (l>>4)*16;     // byte col of this lane's 16B
      bf16x8 ah[4], al[4], bh2[2], bl2[2];
      #pragma unroll
      for (int mb=0;mb<4;mb++){
        int row = wm*64 + mb*16 + (l&15);
        int off = row*128 + (cb ^ ((row&7)<<4));
        ah[mb] = *(const bf16x8*)((const char*)sAh + off);
        al[mb] = *(const bf16x8*)((const char*)sAl + off);
      }
      #pragma unroll
      for (int nb=0;nb<2;nb++){
        int row = wn*32 + nb*16 + (l&15);
        int off = row*128 + (cb ^ ((row&7)<<4));
        bh2[nb] = *(const bf16x8*)((const char*)sBh + off);
        bl2[nb] = *(const bf16x8*)((const char*)sBl + off);
      }
      #pragma unroll
      for (int mb=0;mb<4;mb++)
        #pragma unroll
        for (int nb=0;nb<2;nb++){
          acc[mb][nb] = __builtin_amdgcn_mfma_f32_16x16x32_bf16(ah[mb], bh2[nb], acc[mb][nb], 0,0,0);
          acc[mb][nb] = __builtin_amdgcn_mfma_f32_16x16x32_bf16(ah[mb], bl2[nb], acc[mb][nb], 0,0,0);
          acc[mb][nb] = __builtin_amdgcn_mfma_f32_16x16x32_bf16(al[mb], bh2[nb], acc[mb][nb], 0,0,0);
        }
    }
    __syncthreads();
  }
  // epilogue: C/D layout col=lane&15, row=(lane>>4)*4+reg
  #pragma unroll
  for (int mb=0;mb<4;mb++)
    #pragma unroll
    for (int nb=0;nb<2;nb++)
      #pragma unroll
      for (int r=0;r<4;r++){
        int row = m0 + wm*64 + mb*16 + (l>>4)*4 + r;
        int col = n0 + wn*32 + nb*16 + (l&15);
        float v = acc[mb][nb][r];
        if (EPI == 1) v = v * sigmoid_(v);   // silu
        C[(size_t)row*N + col] = v;
      }
}

// ---------------- fp32 GEMM (only for the tiny x@Wg1, N=64) ----------------
template<int EPI>
__global__ __launch_bounds__(256) void gemm_tile(const float* __restrict__ A,
    const float* __restrict__ W, float* __restrict__ C, int M, int Nc, int K)
{
  __shared__ float As[16][LDP];
  __shared__ float Ws[16][LDP];
  const int tid = threadIdx.x;
  const int tx = tid & 15, ty = tid >> 4;
  const int m0 = blockIdx.x * 64, n0 = blockIdx.y * 64;
  const int flat = tid * 4;
  const int am = flat >> 4, ak = flat & 15;
  const int wk = flat >> 6, wn = flat & 63;
  const float* Aptr = A + (size_t)(m0+am)*K + ak;
  const float* Wptr = W + (size_t)wk*Nc + n0 + wn;
  float acc[4][4] = {};
  float4 av = *(const float4*)Aptr;
  float4 wv = *(const float4*)Wptr;
  for (int k0 = 0; k0 < K; k0 += 16){
    As[ak+0][am]=av.x; As[ak+1][am]=av.y; As[ak+2][am]=av.z; As[ak+3][am]=av.w;
    *(float4*)&Ws[wk][wn] = wv;
    __syncthreads();
    if (k0 + 16 < K){
      av = *(const float4*)(Aptr + k0 + 16);
      wv = *(const float4*)(Wptr + (size_t)(k0+16)*Nc);
    }
    #pragma unroll
    for (int kk=0; kk<16; ++kk){
      float4 ra = *(const float4*)&As[kk][ty*4];
      float4 rw = *(const float4*)&Ws[kk][tx*4];
      float aa[4] = {ra.x,ra.y,ra.z,ra.w};
      float ww[4] = {rw.x,rw.y,rw.z,rw.w};
      #pragma unroll
      for (int i=0;i<4;i++)
        #pragma unroll
        for (int j=0;j<4;j++)
          acc[i][j] = fmaf(aa[i], ww[j], acc[i][j]);
    }
    __syncthreads();
  }
  #pragma unroll
  for (int i=0;i<4;i++){
    float vv[4];
    #pragma unroll
    for (int j=0;j<4;j++){
      float x = acc[i][j];
      if (EPI == 1) x = x * sigmoid_(x);
      vv[j] = x;
    }
    float4 o; o.x=vv[0]; o.y=vv[1]; o.z=vv[2]; o.w=vv[3];
    *(float4*)(C + (size_t)(m0+ty*4+i)*Nc + n0 + tx*4) = o;
  }
}

// ---------------- RoPE in-place on q and k (post-silu) ----------------
__global__ __launch_bounds__(256) void rope_kernel(float* __restrict__ q,
    float* __restrict__ k, const float* __restrict__ ct, const float* __restrict__ st)
{
  int i = blockIdx.x*256 + threadIdx.x;
  const int T = B_*N_*H_*HALF_;            // 2^21
  float* p = (i < T) ? q : k;
  int ii = (i < T) ? i : i - T;
  int j = ii & (HALF_-1);
  int h = (ii >> 5) & (H_-1);
  int n = (ii >> 9) & (N_-1);
  int b = ii >> 20;
  size_t base = ((size_t)(b*N_ + n))*E_ + h*D_;
  float c = ct[n*HALF_ + j], s = st[n*HALF_ + j];
  float x1 = p[base + j], x2 = p[base + HALF_ + j];
  p[base + j]         = x1*c - x2*s;
  p[base + HALF_ + j] = x1*s + x2*c;
}

// ---------------- Pass 1: per-chunk KV outer products ----------------
__global__ __launch_bounds__(256) void chunk_kv_kernel(const float* __restrict__ k,
    const float* __restrict__ v, float* __restrict__ kvbuf)
{
  __shared__ float Ks[CK][LDP];
  __shared__ float Vs[CK][LDP];
  int bid = blockIdx.x;
  int c = bid % NC, bh = bid / NC;
  int b = bh / H_, h = bh % H_;
  int tid = threadIdx.x;
  const float* kbase = k + ((size_t)(b*N_ + c*CK))*E_ + h*D_;
  const float* vbase = v + ((size_t)(b*N_ + c*CK))*E_ + h*D_;
  #pragma unroll
  for (int it=0; it<4; ++it){
    int f4 = it*256 + tid;
    int row = f4 >> 4, c4 = (f4 & 15) << 2;
    *(float4*)&Ks[row][c4] = *(const float4*)(kbase + (size_t)row*E_ + c4);
    *(float4*)&Vs[row][c4] = *(const float4*)(vbase + (size_t)row*E_ + c4);
  }
  __syncthreads();
  int tx = tid & 15, ty = tid >> 4;
  float acc[4][4] = {};
  #pragma unroll 8
  for (int m=0;m<CK;m++){
    float4 ka = *(const float4*)&Ks[m][ty*4];
    float4 va = *(const float4*)&Vs[m][tx*4];
    float aa[4] = {ka.x,ka.y,ka.z,ka.w};
    float ww[4] = {va.x,va.y,va.z,va.w};
    #pragma unroll
    for (int i=0;i<4;i++)
      #pragma unroll
      for (int j=0;j<4;j++)
        acc[i][j] = fmaf(aa[i], ww[j], acc[i][j]);
  }
  float* outp = kvbuf + ((size_t)bh*NC + c)*D_*D_;
  #pragma unroll
  for (int i=0;i<4;i++){
    float4 o; o.x=acc[i][0]; o.y=acc[i][1]; o.z=acc[i][2]; o.w=acc[i][3];
    *(float4*)(outp + (size_t)(ty*4+i)*D_ + tx*4) = o;
  }
}

// ---------------- Pass 2: exclusive prefix scan of chunk KV states ----------------
__global__ __launch_bounds__(256) void kv_scan_kernel(float* __restrict__ kvbuf){
  int bh = blockIdx.x, tid = threadIdx.x;
  float* base = kvbuf + (size_t)bh*NC*D_*D_;
  float run[16] = {};
  for (int c=0;c<NC;c++){
    float* p = base + (size_t)c*D_*D_ + tid;
    #pragma unroll
    for (int s=0;s<16;s++){
      float val = p[s*256];
      p[s*256] = run[s];
      run[s] += val;
    }
  }
}

// ---------------- Pass 3: out = masked(q k^T) v  +  q @ KV_prefix ----------------
__global__ __launch_bounds__(256) void attn_chunk_kernel(const float* __restrict__ q,
    const float* __restrict__ k, const float* __restrict__ v,
    const float* __restrict__ kvbuf, float* __restrict__ attn)
{
  __shared__ float Qs[CK][LDP];
  __shared__ float KSs[CK][LDP];
  __shared__ float Vs[CK][LDP];
  __shared__ float KVs[D_][LDP];
  int bid = blockIdx.x;
  int c = bid % NC, bh = bid / NC;
  int b = bh / H_, h = bh % H_;
  int tid = threadIdx.x;
  const float* qbase = q + ((size_t)(b*N_ + c*CK))*E_ + h*D_;
  const float* kbase = k + ((size_t)(b*N_ + c*CK))*E_ + h*D_;
  const float* vbase = v + ((size_t)(b*N_ + c*CK))*E_ + h*D_;
  const float* kvbase = kvbuf + ((size_t)bh*NC + c)*D_*D_;
  #pragma unroll
  for (int it=0; it<4; ++it){
    int f4 = it*256 + tid;
    int row = f4 >> 4, c4 = (f4 & 15) << 2;
    *(float4*)&Qs[row][c4]  = *(const float4*)(qbase + (size_t)row*E_ + c4);
    *(float4*)&KSs[row][c4] = *(const float4*)(kbase + (size_t)row*E_ + c4);
    *(float4*)&Vs[row][c4]  = *(const float4*)(vbase + (size_t)row*E_ + c4);
    *(float4*)&KVs[row][c4] = *(const float4*)(kvbase + (size_t)f4*4);
  }
  __syncthreads();
  int tx = tid & 15, ty = tid >> 4;
  float accS[4][4] = {};
  #pragma unroll
  for (int dk=0; dk<D_; dk+=4){
    float4 qr[4], kr[4];
    #pragma unroll
    for (int i=0;i<4;i++) qr[i] = *(const float4*)&Qs[ty*4+i][dk];
    #pragma unroll
    for (int j=0;j<4;j++) kr[j] = *(const float4*)&KSs[tx*4+j][dk];
    #pragma unroll
    for (int i=0;i<4;i++)
      #pragma unroll
      for (int j=0;j<4;j++)
        accS[i][j] += qr[i].x*kr[j].x + qr[i].y*kr[j].y
                    + qr[i].z*kr[j].z + qr[i].w*kr[j].w;
  }
  __syncthreads();
  #pragma unroll
  for (int i=0;i<4;i++)
    #pragma unroll
    for (int j=0;j<4;j++){
      int n = ty*4+i, m = tx*4+j;
      KSs[n][m] = (m <= n) ? accS[i][j] : 0.0f;
    }
  __syncthreads();
  float acc[4][4] = {};
  #pragma unroll 4
  for (int m=0;m<CK;m++){
    float4 vv = *(const float4*)&Vs[m][tx*4];
    float ww[4] = {vv.x,vv.y,vv.z,vv.w};
    #pragma unroll
    for (int i=0;i<4;i++){
      float sv = KSs[ty*4+i][m];
      #pragma unroll
      for (int j=0;j<4;j++) acc[i][j] = fmaf(sv, ww[j], acc[i][j]);
    }
  }
  #pragma unroll 4
  for (int dk=0;dk<D_;dk++){
    float4 kvv = *(const float4*)&KVs[dk][tx*4];
    float ww[4] = {kvv.x,kvv.y,kvv.z,kvv.w};
    #pragma unroll
    for (int i=0;i<4;i++){
      float qv = Qs[ty*4+i][dk];
      #pragma unroll
      for (int j=0;j<4;j++) acc[i][j] = fmaf(qv, ww[j], acc[i][j]);
    }
  }
  float* obase = attn + ((size_t)(b*N_ + c*CK))*E_ + h*D_;
  #pragma unroll
  for (int i=0;i<4;i++){
    float4 o; o.x=acc[i][0]; o.y=acc[i][1]; o.z=acc[i][2]; o.w=acc[i][3];
    *(float4*)(obase + (size_t)(ty*4+i)*E_ + tx*4) = o;
  }
}

// ------- gate (sigmoid(g1@Wg2)) * attn, LayerNorm, emit y as hi/lo bf16 -------
__global__ __launch_bounds__(256) void gate_ln_kernel(const float* __restrict__ attn,
    const float* __restrict__ g1, const float* __restrict__ Wg2,
    const float* __restrict__ gamma, const float* __restrict__ beta,
    short* __restrict__ yh, short* __restrict__ yl)
{
  __shared__ float g1s[D_];
  __shared__ float red[8];
  __shared__ float stats[2];
  int r = blockIdx.x, tid = threadIdx.x;
  if (tid < D_) g1s[tid] = g1[(size_t)r*D_ + tid];
  __syncthreads();
  float gacc[4] = {};
  for (int dk=0; dk<D_; ++dk){
    float gv = g1s[dk];
    const float* wrow = Wg2 + (size_t)dk*E_;
    #pragma unroll
    for (int i=0;i<4;i++) gacc[i] = fmaf(gv, wrow[i*256+tid], gacc[i]);
  }
  float vals[4]; float s=0.f, sq=0.f;
  #pragma unroll
  for (int i=0;i<4;i++){
    float a = attn[(size_t)r*E_ + i*256 + tid];
    float val = a * sigmoid_(gacc[i]);
    vals[i] = val; s += val; sq += val*val;
  }
  #pragma unroll
  for (int off=32; off>=1; off>>=1){
    s  += __shfl_down(s,  off, 64);
    sq += __shfl_down(sq, off, 64);
  }
  int lane = tid & 63, wid = tid >> 6;
  if (lane == 0){ red[wid] = s; red[4+wid] = sq; }
  __syncthreads();
  if (tid == 0){
    float ts = red[0]+red[1]+red[2]+red[3];
    float tq = red[4]+red[5]+red[6]+red[7];
    float mu = ts / (float)E_;
    float var = tq / (float)E_ - mu*mu;
    stats[0] = mu; stats[1] = rsqrtf(var + EPS_);
  }
  __syncthreads();
  float mu = stats[0], rs = stats[1];
  #pragma unroll
  for (int i=0;i<4;i++){
    int e = i*256 + tid;
    float yv = (vals[i]-mu)*rs*gamma[e] + beta[e];
    unsigned short hb = f2bf(yv);
    yh[(size_t)r*E_ + e] = (short)hb;
    yl[(size_t)r*E_ + e] = (short)f2bf(yv - bf2f(hb));
  }
}

extern "C" void kernel_launch(void* const* d_in, const int* in_sizes, int n_in,
                              void* d_out, int out_size, void* d_ws, size_t ws_size,
                              hipStream_t stream) {
  const float* x    = (const float*)d_in[0];
  const float* Wq   = (const float*)d_in[1];
  const float* Wk   = (const float*)d_in[2];
  const float* Wv   = (const float*)d_in[3];
  const float* Wo   = (const float*)d_in[4];
  const float* Wg1  = (const float*)d_in[5];
  const float* Wg2  = (const float*)d_in[6];
  const float* gamma= (const float*)d_in[7];
  const float* beta = (const float*)d_in[8];
  float* out = (float*)d_out;

  char* ws = (char*)d_ws;
  const size_t MB = 1024*1024;
  float* q    = (float*)(ws + 0*MB);        // 16 MB
  float* k    = (float*)(ws + 16*MB);       // 16 MB
  float* v    = (float*)(ws + 32*MB);       // 16 MB
  float* attn = (float*)(ws + 48*MB);       // 16 MB
  float* g1   = (float*)(ws + 64*MB);       // 1 MB
  float* kv   = (float*)(ws + 65*MB);       // 16 MB
  float* ct   = (float*)(ws + 81*MB);       // 256 KB
  float* st   = (float*)(ws + 82*MB);       // 256 KB
  short* xh   = (short*)(ws + 83*MB);       // 8 MB
  short* xl   = (short*)(ws + 91*MB);       // 8 MB
  short* yh   = (short*)(ws + 99*MB);       // 8 MB
  short* yl   = (short*)(ws + 107*MB);      // 8 MB
  short* wqh  = (short*)(ws + 115*MB);      // 2 MB each from here
  short* wql  = (short*)(ws + 117*MB);
  short* wkh  = (short*)(ws + 119*MB);
  short* wkl  = (short*)(ws + 121*MB);
  short* wvh  = (short*)(ws + 123*MB);
  short* wvl  = (short*)(ws + 125*MB);
  short* woh  = (short*)(ws + 127*MB);
  short* wol  = (short*)(ws + 129*MB);      // end 131 MB

  dim3 blk(256);
  sincos_kernel<<<dim3(N_*HALF_/256), blk, 0, stream>>>(ct, st);
  xsplit_kernel<<<dim3(BN*E_/4/256), blk, 0, stream>>>(x, xh, xl);
  wsplit_kernel<<<dim3(E_/64, E_/64), blk, 0, stream>>>(Wq, wqh, wql, E_, E_);
  wsplit_kernel<<<dim3(E_/64, E_/64), blk, 0, stream>>>(Wk, wkh, wkl, E_, E_);
  wsplit_kernel<<<dim3(E_/64, E_/64), blk, 0, stream>>>(Wv, wvh, wvl, E_, E_);
  wsplit_kernel<<<dim3(E_/64, E_/64), blk, 0, stream>>>(Wo, woh, wol, E_, E_);

  gemm_mfma<1><<<dim3(BN/128, E_/64), blk, 0, stream>>>(xh, xl, wqh, wql, q, BN, E_, E_);
  gemm_mfma<1><<<dim3(BN/128, E_/64), blk, 0, stream>>>(xh, xl, wkh, wkl, k, BN, E_, E_);
  gemm_mfma<0><<<dim3(BN/128, E_/64), blk, 0, stream>>>(xh, xl, wvh, wvl, v, BN, E_, E_);
  gemm_tile<0><<<dim3(BN/64, 1), blk, 0, stream>>>(x, Wg1, g1, BN, D_, E_);

  rope_kernel<<<dim3(2*B_*N_*H_*HALF_/256), blk, 0, stream>>>(q, k, ct, st);
  chunk_kv_kernel<<<dim3(B_*H_*NC), blk, 0, stream>>>(k, v, kv);
  kv_scan_kernel<<<dim3(B_*H_), blk, 0, stream>>>(kv);
  attn_chunk_kernel<<<dim3(B_*H_*NC), blk, 0, stream>>>(q, k, v, kv, attn);
  gate_ln_kernel<<<dim3(BN), blk, 0, stream>>>(attn, g1, Wg2, gamma, beta, yh, yl);
  gemm_mfma<0><<<dim3(BN/128, E_/64), blk, 0, stream>>>(yh, yl, woh, wol, out, BN, E_, E_);
}

// Round 5
// 299.324 us; speedup vs baseline: 1.4043x; 1.4043x over previous
//
#include <hip/hip_runtime.h>
#include <hip/hip_bf16.h>
#include <math.h>

// Problem constants
#define B_ 2
#define N_ 2048
#define E_ 1024
#define H_ 16
#define D_ 64
#define HALF_ 32
#define CK 64              // attention chunk size
#define NC (N_/CK)         // 32 chunks
#define BN (B_*N_)         // 4096 rows
#define TLD 72             // transposed LDS tile row stride in shorts (144 B, 16B-aligned, 2-way banks)
#define EPS_ 1e-5f

using bf16x8  = __attribute__((ext_vector_type(8))) short;
using f32x4   = __attribute__((ext_vector_type(4))) float;
using short4v = __attribute__((ext_vector_type(4))) short;

__device__ __forceinline__ float sigmoid_(float v){ return 1.0f/(1.0f + __expf(-v)); }

// bf16 bit helpers (RNE)
__device__ __forceinline__ unsigned short f2bf(float f){
  unsigned u = __float_as_uint(f);
  unsigned r = (u + 0x7fffu + ((u>>16)&1u)) >> 16;
  return (unsigned short)r;
}
__device__ __forceinline__ float bf2f(unsigned short h){
  return __uint_as_float(((unsigned)h)<<16);
}

#define GLDS16(gp, lp) __builtin_amdgcn_global_load_lds( \
    (const __attribute__((address_space(1))) void*)(gp), \
    (__attribute__((address_space(3))) void*)(lp), 16, 0, 0)

// ---------------- cos/sin table (double precision — HW-verified variant) ----------------
__global__ __launch_bounds__(256) void sincos_kernel(float* __restrict__ ct,
                                                     float* __restrict__ st){
  int i = blockIdx.x*256 + threadIdx.x;      // i < N_*HALF_
  int n = i >> 5, j = i & (HALF_-1);
  double invf = exp(((double)(-2*j)/(double)D_) * log(10000.0));
  double ang = (double)n * invf;
  ct[i] = (float)cos(ang);
  st[i] = (float)sin(ang);
}

// ---------------- split x (fp32) -> hi/lo bf16 ----------------
__global__ __launch_bounds__(256) void xsplit_kernel(const float* __restrict__ x,
    short* __restrict__ xh, short* __restrict__ xl){
  int i = blockIdx.x*256 + threadIdx.x;   // float4 index
  float4 vv = ((const float4*)x)[i];
  float vs[4] = {vv.x, vv.y, vv.z, vv.w};
  short4v h, l;
  #pragma unroll
  for (int j=0;j<4;j++){
    unsigned short hb = f2bf(vs[j]);
    h[j] = (short)hb;
    l[j] = (short)f2bf(vs[j] - bf2f(hb));
  }
  ((short4v*)xh)[i] = h;
  ((short4v*)xl)[i] = l;
}

// ---------------- transpose + split W[K][N] -> [N][K] hi/lo bf16 ----------------
__global__ __launch_bounds__(256) void wsplit_kernel(const float* __restrict__ W,
    short* __restrict__ Wth, short* __restrict__ Wtl, int K, int N){
  __shared__ float T[64][65];
  int k0 = blockIdx.x*64, n0 = blockIdx.y*64;
  int tid = threadIdx.x;
  #pragma unroll
  for (int it=0; it<4; ++it){
    int idx = it*256 + tid;
    int r = idx >> 4, c = (idx & 15) << 2;
    float4 v = *(const float4*)&W[(size_t)(k0+r)*N + n0 + c];
    T[c+0][r]=v.x; T[c+1][r]=v.y; T[c+2][r]=v.z; T[c+3][r]=v.w;
  }
  __syncthreads();
  #pragma unroll
  for (int it=0; it<2; ++it){
    int idx = it*256 + tid;
    int r = idx >> 3, c8 = (idx & 7) << 3;
    bf16x8 h, l;
    #pragma unroll
    for (int j=0;j<8;j++){
      float v = T[r][c8+j];
      unsigned short hb = f2bf(v);
      h[j] = (short)hb;
      l[j] = (short)f2bf(v - bf2f(hb));
    }
    size_t o = (size_t)(n0+r)*K + k0 + c8;
    *(bf16x8*)&Wth[o] = h;
    *(bf16x8*)&Wtl[o] = l;
  }
}

// ---------------- MFMA split-bf16 GEMM ----------------
// EPI=0: fp32 C. EPI=2: split bf16 -> Ch/Cl. EPI=3: fused QKV epilogue.
template<int EPI>
__global__ __launch_bounds__(256) void gemm_mfma(
    const short* __restrict__ Ah, const short* __restrict__ Al,
    const short* __restrict__ Bh, const short* __restrict__ Bl,
    float* __restrict__ C, short* __restrict__ Ch, short* __restrict__ Cl,
    float* __restrict__ Cq, float* __restrict__ Ck,
    short* __restrict__ Cvh, short* __restrict__ Cvl,
    int M, int N, int K)
{
  __shared__ __align__(16) short sAh[128*64];
  __shared__ __align__(16) short sAl[128*64];
  __shared__ __align__(16) short sBh[64*64];
  __shared__ __align__(16) short sBl[64*64];
  const int tid = threadIdx.x;
  const int l = tid & 63, w = tid >> 6;
  const int wm = w >> 1, wn = w & 1;
  const int m0 = blockIdx.x*128, n0 = blockIdx.y*64;
  const int Kb = K*2;
  f32x4 acc[4][2] = {};

  const char* gAh = (const char*)Ah;
  const char* gAl = (const char*)Al;
  const char* gBh = (const char*)Bh;
  const char* gBl = (const char*)Bl;

  const int nkt = K/64;
  for (int kt = 0; kt < nkt; ++kt){
    const int kbyte = kt*128;
    #pragma unroll
    for (int i=0;i<4;i++){
      int p   = i*4096 + tid*16;
      int row = p >> 7;
      int c   = (p & 127) ^ ((row & 7) << 4);
      size_t go = (size_t)(m0+row)*Kb + kbyte + c;
      char* lb  = (char*)sAh + i*4096 + w*1024;
      char* lb2 = (char*)sAl + i*4096 + w*1024;
      GLDS16(gAh + go, lb);
      GLDS16(gAl + go, lb2);
    }
    #pragma unroll
    for (int i=0;i<2;i++){
      int p   = i*4096 + tid*16;
      int row = p >> 7;
      int c   = (p & 127) ^ ((row & 7) << 4);
      size_t go = (size_t)(n0+row)*Kb + kbyte + c;
      char* lb  = (char*)sBh + i*4096 + w*1024;
      char* lb2 = (char*)sBl + i*4096 + w*1024;
      GLDS16(gBh + go, lb);
      GLDS16(gBl + go, lb2);
    }
    __syncthreads();
    #pragma unroll
    for (int kb=0;kb<2;kb++){
      const int cb = kb*64 + (l>>4)*16;
      bf16x8 ah[4], al[4], bh2[2], bl2[2];
      #pragma unroll
      for (int mb=0;mb<4;mb++){
        int row = wm*64 + mb*16 + (l&15);
        int off = row*128 + (cb ^ ((row&7)<<4));
        ah[mb] = *(const bf16x8*)((const char*)sAh + off);
        al[mb] = *(const bf16x8*)((const char*)sAl + off);
      }
      #pragma unroll
      for (int nb=0;nb<2;nb++){
        int row = wn*32 + nb*16 + (l&15);
        int off = row*128 + (cb ^ ((row&7)<<4));
        bh2[nb] = *(const bf16x8*)((const char*)sBh + off);
        bl2[nb] = *(const bf16x8*)((const char*)sBl + off);
      }
      #pragma unroll
      for (int mb=0;mb<4;mb++)
        #pragma unroll
        for (int nb=0;nb<2;nb++){
          acc[mb][nb] = __builtin_amdgcn_mfma_f32_16x16x32_bf16(ah[mb], bh2[nb], acc[mb][nb], 0,0,0);
          acc[mb][nb] = __builtin_amdgcn_mfma_f32_16x16x32_bf16(ah[mb], bl2[nb], acc[mb][nb], 0,0,0);
          acc[mb][nb] = __builtin_amdgcn_mfma_f32_16x16x32_bf16(al[mb], bh2[nb], acc[mb][nb], 0,0,0);
        }
    }
    __syncthreads();
  }
  #pragma unroll
  for (int mb=0;mb<4;mb++)
    #pragma unroll
    for (int nb=0;nb<2;nb++)
      #pragma unroll
      for (int r=0;r<4;r++){
        int row = m0 + wm*64 + mb*16 + (l>>4)*4 + r;
        int colg = n0 + wn*32 + nb*16 + (l&15);
        float v = acc[mb][nb][r];
        if (EPI == 0){
          C[(size_t)row*N + colg] = v;
        } else if (EPI == 2){
          unsigned short hb = f2bf(v);
          Ch[(size_t)row*N + colg] = (short)hb;
          Cl[(size_t)row*N + colg] = (short)f2bf(v - bf2f(hb));
        } else if (EPI == 3){
          if (colg < 1024){
            Cq[(size_t)row*1024 + colg] = v * sigmoid_(v);
          } else if (colg < 2048){
            Ck[(size_t)row*1024 + colg - 1024] = v * sigmoid_(v);
          } else {
            unsigned short hb = f2bf(v);
            Cvh[(size_t)row*1024 + colg - 2048] = (short)hb;
            Cvl[(size_t)row*1024 + colg - 2048] = (short)f2bf(v - bf2f(hb));
          }
        }
      }
}

// ---------------- RoPE: read post-silu fp32 q,k; write hi/lo bf16 splits ----------------
__global__ __launch_bounds__(256) void rope_kernel(
    const float* __restrict__ qf, const float* __restrict__ kf,
    const float* __restrict__ ct, const float* __restrict__ st,
    short* __restrict__ qh, short* __restrict__ ql,
    short* __restrict__ kh, short* __restrict__ kl)
{
  int i = blockIdx.x*256 + threadIdx.x;       // B*N*H*8 threads
  int j0 = (i & 7) << 2;
  int h  = (i >> 3) & (H_-1);
  int n  = (i >> 7) & (N_-1);
  int b  = i >> 18;
  size_t base = ((size_t)(b*N_ + n))*E_ + h*D_;
  float4 c4 = *(const float4*)(ct + n*HALF_ + j0);
  float4 s4 = *(const float4*)(st + n*HALF_ + j0);
  float cc[4] = {c4.x,c4.y,c4.z,c4.w};
  float ss[4] = {s4.x,s4.y,s4.z,s4.w};
  #pragma unroll
  for (int which=0; which<2; ++which){
    const float* src = which ? kf : qf;
    short* dh = which ? kh : qh;
    short* dl = which ? kl : ql;
    float4 x1 = *(const float4*)(src + base + j0);
    float4 x2 = *(const float4*)(src + base + HALF_ + j0);
    float a1[4] = {x1.x,x1.y,x1.z,x1.w};
    float a2[4] = {x2.x,x2.y,x2.z,x2.w};
    short4v o1h,o1l,o2h,o2l;
    #pragma unroll
    for (int j=0;j<4;j++){
      float r1 = a1[j]*cc[j] - a2[j]*ss[j];
      float r2 = a1[j]*ss[j] + a2[j]*cc[j];
      unsigned short h1 = f2bf(r1), h2 = f2bf(r2);
      o1h[j]=(short)h1; o1l[j]=(short)f2bf(r1 - bf2f(h1));
      o2h[j]=(short)h2; o2l[j]=(short)f2bf(r2 - bf2f(h2));
    }
    *(short4v*)(dh + base + j0) = o1h;
    *(short4v*)(dl + base + j0) = o1l;
    *(short4v*)(dh + base + HALF_ + j0) = o2h;
    *(short4v*)(dl + base + HALF_ + j0) = o2l;
  }
}

// ---------------- Pass 1 (MFMA): per-chunk KV = K^T V outer products ----------------
// Stages K^T [d_in][m] and V^T [d_out][m] hi/lo in padded transposed LDS tiles.
__global__ __launch_bounds__(256) void chunk_kv_kernel(
    const short* __restrict__ kh, const short* __restrict__ kl,
    const short* __restrict__ vh, const short* __restrict__ vl,
    float* __restrict__ kvbuf)
{
  __shared__ __align__(16) short sKth[64*TLD], sKtl[64*TLD];
  __shared__ __align__(16) short sVth[64*TLD], sVtl[64*TLD];
  int bid = blockIdx.x;
  int c = bid & (NC-1), bh = bid >> 5;
  int b = bh >> 4, h = bh & 15;
  int tid = threadIdx.x;
  const int l = tid & 63, w = tid >> 6;
  const size_t rb = ((size_t)(b*N_ + c*CK))*E_ + h*D_;
  #pragma unroll
  for (int it=0; it<4; ++it){
    int f = it*256 + tid;                  // element-quad index
    int m = f >> 4, d0 = (f & 15) << 2;
    short4v a  = *(const short4v*)(kh + rb + (size_t)m*E_ + d0);
    short4v b2 = *(const short4v*)(kl + rb + (size_t)m*E_ + d0);
    short4v cc = *(const short4v*)(vh + rb + (size_t)m*E_ + d0);
    short4v dd = *(const short4v*)(vl + rb + (size_t)m*E_ + d0);
    #pragma unroll
    for (int j=0;j<4;j++){
      sKth[(d0+j)*TLD + m] = a[j];
      sKtl[(d0+j)*TLD + m] = b2[j];
      sVth[(d0+j)*TLD + m] = cc[j];
      sVtl[(d0+j)*TLD + m] = dd[j];
    }
  }
  __syncthreads();
  // out[d_in][d_out] = sum_m K[m][d_in] * V[m][d_out]; wave w owns d_in rows w*16..+15
  f32x4 acc[4] = {};
  #pragma unroll
  for (int ks=0; ks<2; ++ks){
    int acb = ks*64 + (l>>4)*16;            // contraction byte offset (m)
    int arow = w*16 + (l&15);               // d_in
    bf16x8 aH = *(const bf16x8*)((const char*)sKth + arow*(TLD*2) + acb);
    bf16x8 aL = *(const bf16x8*)((const char*)sKtl + arow*(TLD*2) + acb);
    #pragma unroll
    for (int db=0; db<4; ++db){
      int brow = db*16 + (l&15);            // d_out
      bf16x8 bH = *(const bf16x8*)((const char*)sVth + brow*(TLD*2) + acb);
      bf16x8 bL = *(const bf16x8*)((const char*)sVtl + brow*(TLD*2) + acb);
      acc[db] = __builtin_amdgcn_mfma_f32_16x16x32_bf16(aH, bH, acc[db],0,0,0);
      acc[db] = __builtin_amdgcn_mfma_f32_16x16x32_bf16(aH, bL, acc[db],0,0,0);
      acc[db] = __builtin_amdgcn_mfma_f32_16x16x32_bf16(aL, bH, acc[db],0,0,0);
    }
  }
  float* outp = kvbuf + ((size_t)bh*NC + c)*D_*D_;
  #pragma unroll
  for (int db=0;db<4;db++)
    #pragma unroll
    for (int r=0;r<4;r++){
      int din = w*16 + (l>>4)*4 + r;
      int dout = db*16 + (l&15);
      outp[(size_t)din*D_ + dout] = acc[db][r];
    }
}

// ---------------- Pass 2: exclusive prefix scan (parallel over elements) ----------------
__global__ __launch_bounds__(256) void kv_scan_kernel(float* __restrict__ kvbuf){
  int bh = blockIdx.x >> 4, seg = blockIdx.x & 15;
  int e = seg*256 + threadIdx.x;            // 0..4095
  float* base = kvbuf + (size_t)bh*NC*D_*D_ + e;
  float run = 0.f;
  #pragma unroll 4
  for (int c=0;c<NC;c++){
    float v = base[(size_t)c*D_*D_];
    base[(size_t)c*D_*D_] = run;
    run += v;
  }
}

// ---------------- Pass 3 (MFMA): out = masked(q k^T) v + q @ KV_prefix ----------------
__global__ __launch_bounds__(256) void attn_mfma_kernel(
    const short* __restrict__ qh, const short* __restrict__ ql,
    const short* __restrict__ kh, const short* __restrict__ kl,
    const short* __restrict__ vh, const short* __restrict__ vl,
    const float* __restrict__ kvbuf, float* __restrict__ attn)
{
  __shared__ __align__(16) short sQh[4096], sQl[4096];     // [n][d] 128-B rows, XOR-swz
  __shared__ __align__(16) short sKh[4096], sKl[4096];     // [m][d]; reused for S after QK^T
  __shared__ __align__(16) short sVth[64*TLD], sVtl[64*TLD];   // V^T  [d_out][m] padded
  __shared__ __align__(16) short sKVth[64*TLD], sKVtl[64*TLD]; // KV^T [d_out][d_in] padded
  const int tid = threadIdx.x;
  const int l = tid & 63, w = tid >> 6;
  const int bid = blockIdx.x;
  const int c = bid & (NC-1), bh = bid >> 5;
  const int b = bh >> 4, h = bh & 15;
  const size_t rowbase = (size_t)(b*N_ + c*CK);

  // stage q,k via global_load_lds (linear LDS dest, pre-swizzled source)
  #pragma unroll
  for (int p=0;p<2;p++){
    int base = p*4096 + w*1024;
    int db = base + l*16;
    int row = db >> 7, col = db & 127;
    size_t src = ((rowbase + row)*E_ + h*D_)*2 + (size_t)(col ^ ((row&7)<<4));
    GLDS16((const char*)qh + src, (char*)sQh + base);
    GLDS16((const char*)ql + src, (char*)sQl + base);
    GLDS16((const char*)kh + src, (char*)sKh + base);
    GLDS16((const char*)kl + src, (char*)sKl + base);
  }

  // stage V^T (bf16 splits) and KV^T (fp32 -> split here) into padded transposed tiles
  {
    const short* vhb = vh + rowbase*E_ + h*D_;
    const short* vlb = vl + rowbase*E_ + h*D_;
    const float* kvb = kvbuf + ((size_t)bh*NC + c)*D_*D_;
    #pragma unroll
    for (int it=0; it<4; ++it){
      int f = it*256 + tid;
      int m = f >> 4, d0 = (f & 15) << 2;   // V: row m, cols d0..d0+3 ; KV: row d_in=m, cols d_out
      short4v a  = *(const short4v*)(vhb + (size_t)m*E_ + d0);
      short4v b2 = *(const short4v*)(vlb + (size_t)m*E_ + d0);
      float4 kvv = *(const float4*)(kvb + m*D_ + d0);
      float kvs[4] = {kvv.x,kvv.y,kvv.z,kvv.w};
      #pragma unroll
      for (int j=0;j<4;j++){
        sVth[(d0+j)*TLD + m] = a[j];
        sVtl[(d0+j)*TLD + m] = b2[j];
        unsigned short hb = f2bf(kvs[j]);
        sKVth[(d0+j)*TLD + m] = (short)hb;
        sKVtl[(d0+j)*TLD + m] = (short)f2bf(kvs[j] - bf2f(hb));
      }
    }
  }
  __syncthreads();

  // ---- QK^T (3-term split MFMA); wave w owns q-rows w*16..+15 ----
  f32x4 sacc[4] = {};
  #pragma unroll
  for (int ks=0; ks<2; ++ks){
    int arow = w*16 + (l&15);
    int acb = ks*64 + (l>>4)*16;
    int aoff = arow*128 + (acb ^ ((arow&7)<<4));
    bf16x8 aH = *(const bf16x8*)((const char*)sQh + aoff);
    bf16x8 aL = *(const bf16x8*)((const char*)sQl + aoff);
    #pragma unroll
    for (int nb=0;nb<4;nb++){
      int brow = nb*16 + (l&15);
      int boff = brow*128 + (acb ^ ((brow&7)<<4));
      bf16x8 bH = *(const bf16x8*)((const char*)sKh + boff);
      bf16x8 bL = *(const bf16x8*)((const char*)sKl + boff);
      sacc[nb] = __builtin_amdgcn_mfma_f32_16x16x32_bf16(aH, bH, sacc[nb],0,0,0);
      sacc[nb] = __builtin_amdgcn_mfma_f32_16x16x32_bf16(aH, bL, sacc[nb],0,0,0);
      sacc[nb] = __builtin_amdgcn_mfma_f32_16x16x32_bf16(aL, bH, sacc[nb],0,0,0);
    }
  }
  __syncthreads();   // all K reads done; safe to overwrite with S
  // causal mask + split S -> (sKh, sKl), same XOR-swizzled [n][m] layout
  #pragma unroll
  for (int nb=0;nb<4;nb++)
    #pragma unroll
    for (int r=0;r<4;r++){
      int n = w*16 + (l>>4)*4 + r;
      int m = nb*16 + (l&15);
      float sv = (m <= n) ? sacc[nb][r] : 0.0f;
      unsigned short hb = f2bf(sv);
      int off = n*128 + ((2*m) ^ ((n&7)<<4));
      *(short*)((char*)sKh + off) = (short)hb;
      *(short*)((char*)sKl + off) = (short)f2bf(sv - bf2f(hb));
    }
  __syncthreads();

  // ---- PV + q@KV_prefix : B-frags from padded transposed tiles ----
  f32x4 oacc[4] = {};
  #pragma unroll
  for (int ks=0; ks<2; ++ks){
    int arow = w*16 + (l&15);
    int acb = ks*64 + (l>>4)*16;
    int aoff = arow*128 + (acb ^ ((arow&7)<<4));
    bf16x8 sH = *(const bf16x8*)((const char*)sKh + aoff);
    bf16x8 sL = *(const bf16x8*)((const char*)sKl + aoff);
    bf16x8 qH = *(const bf16x8*)((const char*)sQh + aoff);
    bf16x8 qL = *(const bf16x8*)((const char*)sQl + aoff);
    #pragma unroll
    for (int db=0; db<4; ++db){
      int brow = db*16 + (l&15);
      bf16x8 vH  = *(const bf16x8*)((const char*)sVth  + brow*(TLD*2) + acb);
      bf16x8 vL  = *(const bf16x8*)((const char*)sVtl  + brow*(TLD*2) + acb);
      bf16x8 kvH = *(const bf16x8*)((const char*)sKVth + brow*(TLD*2) + acb);
      bf16x8 kvL = *(const bf16x8*)((const char*)sKVtl + brow*(TLD*2) + acb);
      oacc[db] = __builtin_amdgcn_mfma_f32_16x16x32_bf16(sH, vH,  oacc[db],0,0,0);
      oacc[db] = __builtin_amdgcn_mfma_f32_16x16x32_bf16(sH, vL,  oacc[db],0,0,0);
      oacc[db] = __builtin_amdgcn_mfma_f32_16x16x32_bf16(sL, vH,  oacc[db],0,0,0);
      oacc[db] = __builtin_amdgcn_mfma_f32_16x16x32_bf16(qH, kvH, oacc[db],0,0,0);
      oacc[db] = __builtin_amdgcn_mfma_f32_16x16x32_bf16(qH, kvL, oacc[db],0,0,0);
      oacc[db] = __builtin_amdgcn_mfma_f32_16x16x32_bf16(qL, kvH, oacc[db],0,0,0);
    }
  }
  float* ob = attn + rowbase*E_ + h*D_;
  #pragma unroll
  for (int db=0;db<4;db++)
    #pragma unroll
    for (int r=0;r<4;r++){
      int n = w*16 + (l>>4)*4 + r;
      int d = db*16 + (l&15);
      ob[(size_t)n*E_ + d] = oacc[db][r];
    }
}

// ------- gate: sigmoid(g2) * attn, LayerNorm, emit y hi/lo bf16 -------
__global__ __launch_bounds__(256) void gate_ln_kernel(const float* __restrict__ attn,
    const float* __restrict__ g2,
    const float* __restrict__ gamma, const float* __restrict__ beta,
    short* __restrict__ yh, short* __restrict__ yl)
{
  __shared__ float red[8];
  __shared__ float stats[2];
  int r = blockIdx.x, tid = threadIdx.x;
  float vals[4]; float s=0.f, sq=0.f;
  #pragma unroll
  for (int i=0;i<4;i++){
    int e = i*256 + tid;
    float a = attn[(size_t)r*E_ + e];
    float g = g2[(size_t)r*E_ + e];
    float val = a * sigmoid_(g);
    vals[i] = val; s += val; sq += val*val;
  }
  #pragma unroll
  for (int off=32; off>=1; off>>=1){
    s  += __shfl_down(s,  off, 64);
    sq += __shfl_down(sq, off, 64);
  }
  int lane = tid & 63, wid = tid >> 6;
  if (lane == 0){ red[wid] = s; red[4+wid] = sq; }
  __syncthreads();
  if (tid == 0){
    float ts = red[0]+red[1]+red[2]+red[3];
    float tq = red[4]+red[5]+red[6]+red[7];
    float mu = ts / (float)E_;
    float var = tq / (float)E_ - mu*mu;
    stats[0] = mu; stats[1] = rsqrtf(var + EPS_);
  }
  __syncthreads();
  float mu = stats[0], rs = stats[1];
  #pragma unroll
  for (int i=0;i<4;i++){
    int e = i*256 + tid;
    float yv = (vals[i]-mu)*rs*gamma[e] + beta[e];
    unsigned short hb = f2bf(yv);
    yh[(size_t)r*E_ + e] = (short)hb;
    yl[(size_t)r*E_ + e] = (short)f2bf(yv - bf2f(hb));
  }
}

extern "C" void kernel_launch(void* const* d_in, const int* in_sizes, int n_in,
                              void* d_out, int out_size, void* d_ws, size_t ws_size,
                              hipStream_t stream) {
  const float* x    = (const float*)d_in[0];
  const float* Wq   = (const float*)d_in[1];
  const float* Wk   = (const float*)d_in[2];
  const float* Wv   = (const float*)d_in[3];
  const float* Wo   = (const float*)d_in[4];
  const float* Wg1  = (const float*)d_in[5];
  const float* Wg2  = (const float*)d_in[6];
  const float* gamma= (const float*)d_in[7];
  const float* beta = (const float*)d_in[8];
  float* out = (float*)d_out;

  char* ws = (char*)d_ws;
  const size_t MB = 1024*1024;
  float* qf    = (float*)(ws + 0*MB);       // 16MB; reused as g2 later
  float* kf    = (float*)(ws + 16*MB);      // 16MB; reused as attn later
  short* xh    = (short*)(ws + 32*MB);      // 8MB; reused as yh later
  short* xl    = (short*)(ws + 40*MB);      // 8MB; reused as yl later
  short* vh    = (short*)(ws + 48*MB);      // 8MB
  short* vl    = (short*)(ws + 56*MB);      // 8MB
  short* qhb   = (short*)(ws + 64*MB);      // 8MB
  short* qlb   = (short*)(ws + 72*MB);      // 8MB
  short* khb   = (short*)(ws + 80*MB);      // 8MB
  short* klb   = (short*)(ws + 88*MB);      // 8MB
  float* kv    = (float*)(ws + 96*MB);      // 16MB
  short* wqkvh = (short*)(ws + 112*MB);     // 6MB
  short* wqkvl = (short*)(ws + 118*MB);     // 6MB
  short* woh   = (short*)(ws + 124*MB);     // 2MB
  short* wol   = (short*)(ws + 126*MB);     // 2MB
  float* ct    = (float*)(ws + 128*MB);                 // 256KB
  float* st    = (float*)(ws + 128*MB + 256*1024);      // 256KB
  short* g1h   = (short*)(ws + 129*MB);                 // 512KB
  short* g1l   = (short*)(ws + 129*MB + 512*1024);      // 512KB
  short* wg1h  = (short*)(ws + 130*MB);                 // 128KB
  short* wg1l  = (short*)(ws + 130*MB + 128*1024);
  short* wg2h  = (short*)(ws + 130*MB + 256*1024);
  short* wg2l  = (short*)(ws + 130*MB + 384*1024);      // end ~130.5MB
  float* g2    = qf;     // qf dead after rope
  float* attnb = kf;     // kf dead after rope
  short* yh    = xh;     // xh dead after QKV+g1 gemms
  short* yl    = xl;

  dim3 blk(256);
  sincos_kernel<<<dim3(N_*HALF_/256), blk, 0, stream>>>(ct, st);
  xsplit_kernel<<<dim3(BN*E_/4/256), blk, 0, stream>>>(x, xh, xl);
  wsplit_kernel<<<dim3(16,16), blk, 0, stream>>>(Wq, wqkvh,               wqkvl,               E_, E_);
  wsplit_kernel<<<dim3(16,16), blk, 0, stream>>>(Wk, wqkvh + 1024*1024,   wqkvl + 1024*1024,   E_, E_);
  wsplit_kernel<<<dim3(16,16), blk, 0, stream>>>(Wv, wqkvh + 2048*1024,   wqkvl + 2048*1024,   E_, E_);
  wsplit_kernel<<<dim3(16,16), blk, 0, stream>>>(Wo, woh, wol, E_, E_);
  wsplit_kernel<<<dim3(16,1),  blk, 0, stream>>>(Wg1, wg1h, wg1l, E_, D_);
  wsplit_kernel<<<dim3(1,16),  blk, 0, stream>>>(Wg2, wg2h, wg2l, D_, E_);

  // fused QKV GEMM (N=3072): q,k fp32+silu; v split bf16
  gemm_mfma<3><<<dim3(BN/128, 3072/64), blk, 0, stream>>>(
      xh, xl, wqkvh, wqkvl, nullptr, nullptr, nullptr, qf, kf, vh, vl, BN, 3072, E_);
  // g1 = x @ Wg1 (split bf16 out)
  gemm_mfma<2><<<dim3(BN/128, 1), blk, 0, stream>>>(
      xh, xl, wg1h, wg1l, nullptr, g1h, g1l, nullptr, nullptr, nullptr, nullptr, BN, D_, E_);
  rope_kernel<<<dim3(BN*H_*8/256), blk, 0, stream>>>(qf, kf, ct, st, qhb, qlb, khb, klb);
  // g2 = g1 @ Wg2 (fp32 out, into qf space — qf dead after rope)
  gemm_mfma<0><<<dim3(BN/128, E_/64), blk, 0, stream>>>(
      g1h, g1l, wg2h, wg2l, g2, nullptr, nullptr, nullptr, nullptr, nullptr, nullptr, BN, E_, D_);
  chunk_kv_kernel<<<dim3(B_*H_*NC), blk, 0, stream>>>(khb, klb, vh, vl, kv);
  kv_scan_kernel<<<dim3(B_*H_*16), blk, 0, stream>>>(kv);
  attn_mfma_kernel<<<dim3(B_*H_*NC), blk, 0, stream>>>(qhb, qlb, khb, klb, vh, vl, kv, attnb);
  gate_ln_kernel<<<dim3(BN), blk, 0, stream>>>(attnb, g2, gamma, beta, yh, yl);
  gemm_mfma<0><<<dim3(BN/128, E_/64), blk, 0, stream>>>(
      yh, yl, woh, wol, out, nullptr, nullptr, nullptr, nullptr, nullptr, nullptr, BN, E_, E_);
}

// Round 6
// 274.769 us; speedup vs baseline: 1.5298x; 1.0894x over previous
//
#include <hip/hip_runtime.h>
#include <hip/hip_bf16.h>
#include <math.h>

// Problem constants
#define B_ 2
#define N_ 2048
#define E_ 1024
#define H_ 16
#define D_ 64
#define HALF_ 32
#define CK 64              // attention chunk size
#define NC (N_/CK)         // 32 chunks
#define BN (B_*N_)         // 4096 rows
#define TLD 72             // transposed LDS tile row stride in shorts (144 B, 16B-aligned, 2-way banks)
#define EPS_ 1e-5f
#define NQKV 3200          // 1024 q + 1024 k + 1024 v + 64 g1 + 64 pad

using bf16x8  = __attribute__((ext_vector_type(8))) short;
using f32x4   = __attribute__((ext_vector_type(4))) float;
using short4v = __attribute__((ext_vector_type(4))) short;

__device__ __forceinline__ float sigmoid_(float v){ return 1.0f/(1.0f + __expf(-v)); }

// bf16 bit helpers (RNE)
__device__ __forceinline__ unsigned short f2bf(float f){
  unsigned u = __float_as_uint(f);
  unsigned r = (u + 0x7fffu + ((u>>16)&1u)) >> 16;
  return (unsigned short)r;
}
__device__ __forceinline__ float bf2f(unsigned short h){
  return __uint_as_float(((unsigned)h)<<16);
}

#define GLDS16(gp, lp) __builtin_amdgcn_global_load_lds( \
    (const __attribute__((address_space(1))) void*)(gp), \
    (__attribute__((address_space(3))) void*)(lp), 16, 0, 0)

// ---------------- cos/sin table (double precision — HW-verified variant) ----------------
__global__ __launch_bounds__(256) void sincos_kernel(float* __restrict__ ct,
                                                     float* __restrict__ st){
  int i = blockIdx.x*256 + threadIdx.x;      // i < N_*HALF_
  int n = i >> 5, j = i & (HALF_-1);
  double invf = exp(((double)(-2*j)/(double)D_) * log(10000.0));
  double ang = (double)n * invf;
  ct[i] = (float)cos(ang);
  st[i] = (float)sin(ang);
}

// ---------------- split x (fp32) -> hi/lo bf16 ----------------
__global__ __launch_bounds__(256) void xsplit_kernel(const float* __restrict__ x,
    short* __restrict__ xh, short* __restrict__ xl){
  int i = blockIdx.x*256 + threadIdx.x;   // float4 index
  float4 vv = ((const float4*)x)[i];
  float vs[4] = {vv.x, vv.y, vv.z, vv.w};
  short4v h, l;
  #pragma unroll
  for (int j=0;j<4;j++){
    unsigned short hb = f2bf(vs[j]);
    h[j] = (short)hb;
    l[j] = (short)f2bf(vs[j] - bf2f(hb));
  }
  ((short4v*)xh)[i] = h;
  ((short4v*)xl)[i] = l;
}

// ---------------- zero-fill pad rows of the fused weight buffer ----------------
__global__ __launch_bounds__(256) void zfill_kernel(short* __restrict__ a,
                                                    short* __restrict__ b){
  int i = blockIdx.x*256 + threadIdx.x;   // short4 index, 64*1024/4 = 16384
  short4v z = {0,0,0,0};
  ((short4v*)a)[i] = z;
  ((short4v*)b)[i] = z;
}

// ---------------- transpose + split W[K][N] -> [N][K] hi/lo bf16 ----------------
__global__ __launch_bounds__(256) void wsplit_kernel(const float* __restrict__ W,
    short* __restrict__ Wth, short* __restrict__ Wtl, int K, int N){
  __shared__ float T[64][65];
  int k0 = blockIdx.x*64, n0 = blockIdx.y*64;
  int tid = threadIdx.x;
  #pragma unroll
  for (int it=0; it<4; ++it){
    int idx = it*256 + tid;
    int r = idx >> 4, c = (idx & 15) << 2;
    float4 v = *(const float4*)&W[(size_t)(k0+r)*N + n0 + c];
    T[c+0][r]=v.x; T[c+1][r]=v.y; T[c+2][r]=v.z; T[c+3][r]=v.w;
  }
  __syncthreads();
  #pragma unroll
  for (int it=0; it<2; ++it){
    int idx = it*256 + tid;
    int r = idx >> 3, c8 = (idx & 7) << 3;
    bf16x8 h, l;
    #pragma unroll
    for (int j=0;j<8;j++){
      float v = T[r][c8+j];
      unsigned short hb = f2bf(v);
      h[j] = (short)hb;
      l[j] = (short)f2bf(v - bf2f(hb));
    }
    size_t o = (size_t)(n0+r)*K + k0 + c8;
    *(bf16x8*)&Wth[o] = h;
    *(bf16x8*)&Wtl[o] = l;
  }
}

// ---------------- MFMA split-bf16 GEMM, 128x128 tile ----------------
// EPI=0: fp32 C[M][N].
// EPI=3: fused QKV+g1 epilogue: cols 0..1023 q (silu+rope, split), 1024..2047 k
//        (silu+rope, split), 2048..3071 v (split), 3072..3135 g1 (split), rest drop.
template<int EPI>
__global__ __launch_bounds__(256,2) void gemm_mfma(
    const short* __restrict__ Ah, const short* __restrict__ Al,
    const short* __restrict__ Bh, const short* __restrict__ Bl,
    float* __restrict__ C,
    short* __restrict__ Qh, short* __restrict__ Ql,
    short* __restrict__ Kh, short* __restrict__ Kl,
    short* __restrict__ Vh, short* __restrict__ Vl,
    short* __restrict__ G1h, short* __restrict__ G1l,
    const float* __restrict__ ct, const float* __restrict__ st,
    int M, int N, int K)
{
  __shared__ __align__(16) short sAh[128*64];
  __shared__ __align__(16) short sAl[128*64];
  __shared__ __align__(16) short sBh[128*64];
  __shared__ __align__(16) short sBl[128*64];
  const int tid = threadIdx.x;
  const int l = tid & 63, w = tid >> 6;
  const int wm = w >> 1, wn = w & 1;
  const int m0 = blockIdx.x*128, n0 = blockIdx.y*128;
  const int Kb = K*2;
  f32x4 acc[4][4] = {};

  const char* gAh = (const char*)Ah;
  const char* gAl = (const char*)Al;
  const char* gBh = (const char*)Bh;
  const char* gBl = (const char*)Bl;

  const int nkt = K/64;
  for (int kt = 0; kt < nkt; ++kt){
    const int kbyte = kt*128;
    #pragma unroll
    for (int i=0;i<4;i++){
      int p   = i*4096 + tid*16;
      int row = p >> 7;
      int c   = (p & 127) ^ ((row & 7) << 4);
      size_t goA = (size_t)(m0+row)*Kb + kbyte + c;
      size_t goB = (size_t)(n0+row)*Kb + kbyte + c;
      char* lbase = (char*)nullptr;
      (void)lbase;
      GLDS16(gAh + goA, (char*)sAh + i*4096 + w*1024);
      GLDS16(gAl + goA, (char*)sAl + i*4096 + w*1024);
      GLDS16(gBh + goB, (char*)sBh + i*4096 + w*1024);
      GLDS16(gBl + goB, (char*)sBl + i*4096 + w*1024);
    }
    __syncthreads();
    #pragma unroll
    for (int kb=0;kb<2;kb++){
      const int cb = kb*64 + (l>>4)*16;
      bf16x8 ah[4], al[4], bh2[4], bl2[4];
      #pragma unroll
      for (int mb=0;mb<4;mb++){
        int row = wm*64 + mb*16 + (l&15);
        int off = row*128 + (cb ^ ((row&7)<<4));
        ah[mb] = *(const bf16x8*)((const char*)sAh + off);
        al[mb] = *(const bf16x8*)((const char*)sAl + off);
      }
      #pragma unroll
      for (int nb=0;nb<4;nb++){
        int row = wn*64 + nb*16 + (l&15);
        int off = row*128 + (cb ^ ((row&7)<<4));
        bh2[nb] = *(const bf16x8*)((const char*)sBh + off);
        bl2[nb] = *(const bf16x8*)((const char*)sBl + off);
      }
      #pragma unroll
      for (int mb=0;mb<4;mb++)
        #pragma unroll
        for (int nb=0;nb<4;nb++){
          acc[mb][nb] = __builtin_amdgcn_mfma_f32_16x16x32_bf16(ah[mb], bh2[nb], acc[mb][nb], 0,0,0);
          acc[mb][nb] = __builtin_amdgcn_mfma_f32_16x16x32_bf16(ah[mb], bl2[nb], acc[mb][nb], 0,0,0);
          acc[mb][nb] = __builtin_amdgcn_mfma_f32_16x16x32_bf16(al[mb], bh2[nb], acc[mb][nb], 0,0,0);
        }
    }
    __syncthreads();
  }

  if (EPI == 0){
    #pragma unroll
    for (int mb=0;mb<4;mb++)
      #pragma unroll
      for (int nb=0;nb<4;nb++)
        #pragma unroll
        for (int r=0;r<4;r++){
          int row = m0 + wm*64 + mb*16 + (l>>4)*4 + r;
          int colg = n0 + wn*64 + nb*16 + (l&15);
          C[(size_t)row*N + colg] = acc[mb][nb][r];
        }
  } else {
    const int colg0 = n0 + wn*64;          // wave-uniform 64-col span
    if (colg0 < 2048){
      // q or k : silu then rope (pairs nb <-> nb+2 are in-thread), split bf16
      short* dh = (colg0 < 1024) ? Qh : Kh;
      short* dl = (colg0 < 1024) ? Ql : Kl;
      const int ebase = colg0 & 1023;      // head*64 within [row][1024]
      #pragma unroll
      for (int mb=0;mb<4;mb++)
        #pragma unroll
        for (int nbp=0;nbp<2;nbp++)
          #pragma unroll
          for (int r=0;r<4;r++){
            int row = m0 + wm*64 + mb*16 + (l>>4)*4 + r;
            int d1 = nbp*16 + (l&15);      // 0..31
            float a1 = acc[mb][nbp][r];
            float a2 = acc[mb][nbp+2][r];
            float x1 = a1 * sigmoid_(a1);  // silu
            float x2 = a2 * sigmoid_(a2);
            int n = row & (N_-1);
            float cv = ct[n*HALF_ + d1];
            float sv = st[n*HALF_ + d1];
            float r1 = x1*cv - x2*sv;
            float r2 = x1*sv + x2*cv;
            size_t o1 = (size_t)row*E_ + ebase + d1;
            size_t o2 = o1 + HALF_;
            unsigned short h1 = f2bf(r1);
            dh[o1] = (short)h1; dl[o1] = (short)f2bf(r1 - bf2f(h1));
            unsigned short h2 = f2bf(r2);
            dh[o2] = (short)h2; dl[o2] = (short)f2bf(r2 - bf2f(h2));
          }
    } else if (colg0 < 3072){
      // v : plain split
      #pragma unroll
      for (int mb=0;mb<4;mb++)
        #pragma unroll
        for (int nb=0;nb<4;nb++)
          #pragma unroll
          for (int r=0;r<4;r++){
            int row = m0 + wm*64 + mb*16 + (l>>4)*4 + r;
            int e = colg0 - 2048 + nb*16 + (l&15);
            float v = acc[mb][nb][r];
            unsigned short hb = f2bf(v);
            Vh[(size_t)row*E_ + e] = (short)hb;
            Vl[(size_t)row*E_ + e] = (short)f2bf(v - bf2f(hb));
          }
    } else if (colg0 < 3136){
      // g1 : plain split, row stride 64
      #pragma unroll
      for (int mb=0;mb<4;mb++)
        #pragma unroll
        for (int nb=0;nb<4;nb++)
          #pragma unroll
          for (int r=0;r<4;r++){
            int row = m0 + wm*64 + mb*16 + (l>>4)*4 + r;
            int e = nb*16 + (l&15);        // colg0 == 3072 here
            float v = acc[mb][nb][r];
            unsigned short hb = f2bf(v);
            G1h[(size_t)row*D_ + e] = (short)hb;
            G1l[(size_t)row*D_ + e] = (short)f2bf(v - bf2f(hb));
          }
    }
    // colg0 >= 3136: padding, discard
  }
}

// ---------------- Pass 1 (MFMA): per-chunk KV = K^T V outer products ----------------
__global__ __launch_bounds__(256) void chunk_kv_kernel(
    const short* __restrict__ kh, const short* __restrict__ kl,
    const short* __restrict__ vh, const short* __restrict__ vl,
    float* __restrict__ kvbuf)
{
  __shared__ __align__(16) short sKth[64*TLD], sKtl[64*TLD];
  __shared__ __align__(16) short sVth[64*TLD], sVtl[64*TLD];
  int bid = blockIdx.x;
  int c = bid & (NC-1), bh = bid >> 5;
  int b = bh >> 4, h = bh & 15;
  int tid = threadIdx.x;
  const int l = tid & 63, w = tid >> 6;
  const size_t rb = ((size_t)(b*N_ + c*CK))*E_ + h*D_;
  #pragma unroll
  for (int it=0; it<4; ++it){
    int f = it*256 + tid;                  // element-quad index
    int m = f >> 4, d0 = (f & 15) << 2;
    short4v a  = *(const short4v*)(kh + rb + (size_t)m*E_ + d0);
    short4v b2 = *(const short4v*)(kl + rb + (size_t)m*E_ + d0);
    short4v cc = *(const short4v*)(vh + rb + (size_t)m*E_ + d0);
    short4v dd = *(const short4v*)(vl + rb + (size_t)m*E_ + d0);
    #pragma unroll
    for (int j=0;j<4;j++){
      sKth[(d0+j)*TLD + m] = a[j];
      sKtl[(d0+j)*TLD + m] = b2[j];
      sVth[(d0+j)*TLD + m] = cc[j];
      sVtl[(d0+j)*TLD + m] = dd[j];
    }
  }
  __syncthreads();
  // out[d_in][d_out] = sum_m K[m][d_in] * V[m][d_out]; wave w owns d_in rows w*16..+15
  f32x4 acc[4] = {};
  #pragma unroll
  for (int ks=0; ks<2; ++ks){
    int acb = ks*64 + (l>>4)*16;            // contraction byte offset (m)
    int arow = w*16 + (l&15);               // d_in
    bf16x8 aH = *(const bf16x8*)((const char*)sKth + arow*(TLD*2) + acb);
    bf16x8 aL = *(const bf16x8*)((const char*)sKtl + arow*(TLD*2) + acb);
    #pragma unroll
    for (int db=0; db<4; ++db){
      int brow = db*16 + (l&15);            // d_out
      bf16x8 bH = *(const bf16x8*)((const char*)sVth + brow*(TLD*2) + acb);
      bf16x8 bL = *(const bf16x8*)((const char*)sVtl + brow*(TLD*2) + acb);
      acc[db] = __builtin_amdgcn_mfma_f32_16x16x32_bf16(aH, bH, acc[db],0,0,0);
      acc[db] = __builtin_amdgcn_mfma_f32_16x16x32_bf16(aH, bL, acc[db],0,0,0);
      acc[db] = __builtin_amdgcn_mfma_f32_16x16x32_bf16(aL, bH, acc[db],0,0,0);
    }
  }
  float* outp = kvbuf + ((size_t)bh*NC + c)*D_*D_;
  #pragma unroll
  for (int db=0;db<4;db++)
    #pragma unroll
    for (int r=0;r<4;r++){
      int din = w*16 + (l>>4)*4 + r;
      int dout = db*16 + (l&15);
      outp[(size_t)din*D_ + dout] = acc[db][r];
    }
}

// ---------------- Pass 2: exclusive prefix scan (parallel over elements) ----------------
__global__ __launch_bounds__(256) void kv_scan_kernel(float* __restrict__ kvbuf){
  int bh = blockIdx.x >> 4, seg = blockIdx.x & 15;
  int e = seg*256 + threadIdx.x;            // 0..4095
  float* base = kvbuf + (size_t)bh*NC*D_*D_ + e;
  float run = 0.f;
  #pragma unroll 4
  for (int c=0;c<NC;c++){
    float v = base[(size_t)c*D_*D_];
    base[(size_t)c*D_*D_] = run;
    run += v;
  }
}

// ---------------- Pass 3 (MFMA): out = masked(q k^T) v + q @ KV_prefix ----------------
__global__ __launch_bounds__(256) void attn_mfma_kernel(
    const short* __restrict__ qh, const short* __restrict__ ql,
    const short* __restrict__ kh, const short* __restrict__ kl,
    const short* __restrict__ vh, const short* __restrict__ vl,
    const float* __restrict__ kvbuf, float* __restrict__ attn)
{
  __shared__ __align__(16) short sQh[4096], sQl[4096];     // [n][d] 128-B rows, XOR-swz
  __shared__ __align__(16) short sKh[4096], sKl[4096];     // [m][d]; reused for S after QK^T
  __shared__ __align__(16) short sVth[64*TLD], sVtl[64*TLD];   // V^T  [d_out][m] padded
  __shared__ __align__(16) short sKVth[64*TLD], sKVtl[64*TLD]; // KV^T [d_out][d_in] padded
  const int tid = threadIdx.x;
  const int l = tid & 63, w = tid >> 6;
  const int bid = blockIdx.x;
  const int c = bid & (NC-1), bh = bid >> 5;
  const int b = bh >> 4, h = bh & 15;
  const size_t rowbase = (size_t)(b*N_ + c*CK);

  // stage q,k via global_load_lds (linear LDS dest, pre-swizzled source)
  #pragma unroll
  for (int p=0;p<2;p++){
    int base = p*4096 + w*1024;
    int db = base + l*16;
    int row = db >> 7, col = db & 127;
    size_t src = ((rowbase + row)*E_ + h*D_)*2 + (size_t)(col ^ ((row&7)<<4));
    GLDS16((const char*)qh + src, (char*)sQh + base);
    GLDS16((const char*)ql + src, (char*)sQl + base);
    GLDS16((const char*)kh + src, (char*)sKh + base);
    GLDS16((const char*)kl + src, (char*)sKl + base);
  }

  // stage V^T (bf16 splits) and KV^T (fp32 -> split here) into padded transposed tiles
  {
    const short* vhb = vh + rowbase*E_ + h*D_;
    const short* vlb = vl + rowbase*E_ + h*D_;
    const float* kvb = kvbuf + ((size_t)bh*NC + c)*D_*D_;
    #pragma unroll
    for (int it=0; it<4; ++it){
      int f = it*256 + tid;
      int m = f >> 4, d0 = (f & 15) << 2;   // V: row m, cols d0..d0+3 ; KV: row d_in=m, cols d_out
      short4v a  = *(const short4v*)(vhb + (size_t)m*E_ + d0);
      short4v b2 = *(const short4v*)(vlb + (size_t)m*E_ + d0);
      float4 kvv = *(const float4*)(kvb + m*D_ + d0);
      float kvs[4] = {kvv.x,kvv.y,kvv.z,kvv.w};
      #pragma unroll
      for (int j=0;j<4;j++){
        sVth[(d0+j)*TLD + m] = a[j];
        sVtl[(d0+j)*TLD + m] = b2[j];
        unsigned short hb = f2bf(kvs[j]);
        sKVth[(d0+j)*TLD + m] = (short)hb;
        sKVtl[(d0+j)*TLD + m] = (short)f2bf(kvs[j] - bf2f(hb));
      }
    }
  }
  __syncthreads();

  // ---- QK^T (3-term split MFMA); wave w owns q-rows w*16..+15 ----
  f32x4 sacc[4] = {};
  #pragma unroll
  for (int ks=0; ks<2; ++ks){
    int arow = w*16 + (l&15);
    int acb = ks*64 + (l>>4)*16;
    int aoff = arow*128 + (acb ^ ((arow&7)<<4));
    bf16x8 aH = *(const bf16x8*)((const char*)sQh + aoff);
    bf16x8 aL = *(const bf16x8*)((const char*)sQl + aoff);
    #pragma unroll
    for (int nb=0;nb<4;nb++){
      int brow = nb*16 + (l&15);
      int boff = brow*128 + (acb ^ ((brow&7)<<4));
      bf16x8 bH = *(const bf16x8*)((const char*)sKh + boff);
      bf16x8 bL = *(const bf16x8*)((const char*)sKl + boff);
      sacc[nb] = __builtin_amdgcn_mfma_f32_16x16x32_bf16(aH, bH, sacc[nb],0,0,0);
      sacc[nb] = __builtin_amdgcn_mfma_f32_16x16x32_bf16(aH, bL, sacc[nb],0,0,0);
      sacc[nb] = __builtin_amdgcn_mfma_f32_16x16x32_bf16(aL, bH, sacc[nb],0,0,0);
    }
  }
  __syncthreads();   // all K reads done; safe to overwrite with S
  // causal mask + split S -> (sKh, sKl), same XOR-swizzled [n][m] layout
  #pragma unroll
  for (int nb=0;nb<4;nb++)
    #pragma unroll
    for (int r=0;r<4;r++){
      int n = w*16 + (l>>4)*4 + r;
      int m = nb*16 + (l&15);
      float sv = (m <= n) ? sacc[nb][r] : 0.0f;
      unsigned short hb = f2bf(sv);
      int off = n*128 + ((2*m) ^ ((n&7)<<4));
      *(short*)((char*)sKh + off) = (short)hb;
      *(short*)((char*)sKl + off) = (short)f2bf(sv - bf2f(hb));
    }
  __syncthreads();

  // ---- PV + q@KV_prefix : B-frags from padded transposed tiles ----
  f32x4 oacc[4] = {};
  #pragma unroll
  for (int ks=0; ks<2; ++ks){
    int arow = w*16 + (l&15);
    int acb = ks*64 + (l>>4)*16;
    int aoff = arow*128 + (acb ^ ((arow&7)<<4));
    bf16x8 sH = *(const bf16x8*)((const char*)sKh + aoff);
    bf16x8 sL = *(const bf16x8*)((const char*)sKl + aoff);
    bf16x8 qH = *(const bf16x8*)((const char*)sQh + aoff);
    bf16x8 qL = *(const bf16x8*)((const char*)sQl + aoff);
    #pragma unroll
    for (int db=0; db<4; ++db){
      int brow = db*16 + (l&15);
      bf16x8 vH  = *(const bf16x8*)((const char*)sVth  + brow*(TLD*2) + acb);
      bf16x8 vL  = *(const bf16x8*)((const char*)sVtl  + brow*(TLD*2) + acb);
      bf16x8 kvH = *(const bf16x8*)((const char*)sKVth + brow*(TLD*2) + acb);
      bf16x8 kvL = *(const bf16x8*)((const char*)sKVtl + brow*(TLD*2) + acb);
      oacc[db] = __builtin_amdgcn_mfma_f32_16x16x32_bf16(sH, vH,  oacc[db],0,0,0);
      oacc[db] = __builtin_amdgcn_mfma_f32_16x16x32_bf16(sH, vL,  oacc[db],0,0,0);
      oacc[db] = __builtin_amdgcn_mfma_f32_16x16x32_bf16(sL, vH,  oacc[db],0,0,0);
      oacc[db] = __builtin_amdgcn_mfma_f32_16x16x32_bf16(qH, kvH, oacc[db],0,0,0);
      oacc[db] = __builtin_amdgcn_mfma_f32_16x16x32_bf16(qH, kvL, oacc[db],0,0,0);
      oacc[db] = __builtin_amdgcn_mfma_f32_16x16x32_bf16(qL, kvH, oacc[db],0,0,0);
    }
  }
  float* ob = attn + rowbase*E_ + h*D_;
  #pragma unroll
  for (int db=0;db<4;db++)
    #pragma unroll
    for (int r=0;r<4;r++){
      int n = w*16 + (l>>4)*4 + r;
      int d = db*16 + (l&15);
      ob[(size_t)n*E_ + d] = oacc[db][r];
    }
}

// ------- gate: sigmoid(g2) * attn, LayerNorm, emit y hi/lo bf16 -------
__global__ __launch_bounds__(256) void gate_ln_kernel(const float* __restrict__ attn,
    const float* __restrict__ g2,
    const float* __restrict__ gamma, const float* __restrict__ beta,
    short* __restrict__ yh, short* __restrict__ yl)
{
  __shared__ float red[8];
  __shared__ float stats[2];
  int r = blockIdx.x, tid = threadIdx.x;
  float vals[4]; float s=0.f, sq=0.f;
  #pragma unroll
  for (int i=0;i<4;i++){
    int e = i*256 + tid;
    float a = attn[(size_t)r*E_ + e];
    float g = g2[(size_t)r*E_ + e];
    float val = a * sigmoid_(g);
    vals[i] = val; s += val; sq += val*val;
  }
  #pragma unroll
  for (int off=32; off>=1; off>>=1){
    s  += __shfl_down(s,  off, 64);
    sq += __shfl_down(sq, off, 64);
  }
  int lane = tid & 63, wid = tid >> 6;
  if (lane == 0){ red[wid] = s; red[4+wid] = sq; }
  __syncthreads();
  if (tid == 0){
    float ts = red[0]+red[1]+red[2]+red[3];
    float tq = red[4]+red[5]+red[6]+red[7];
    float mu = ts / (float)E_;
    float var = tq / (float)E_ - mu*mu;
    stats[0] = mu; stats[1] = rsqrtf(var + EPS_);
  }
  __syncthreads();
  float mu = stats[0], rs = stats[1];
  #pragma unroll
  for (int i=0;i<4;i++){
    int e = i*256 + tid;
    float yv = (vals[i]-mu)*rs*gamma[e] + beta[e];
    unsigned short hb = f2bf(yv);
    yh[(size_t)r*E_ + e] = (short)hb;
    yl[(size_t)r*E_ + e] = (short)f2bf(yv - bf2f(hb));
  }
}

extern "C" void kernel_launch(void* const* d_in, const int* in_sizes, int n_in,
                              void* d_out, int out_size, void* d_ws, size_t ws_size,
                              hipStream_t stream) {
  const float* x    = (const float*)d_in[0];
  const float* Wq   = (const float*)d_in[1];
  const float* Wk   = (const float*)d_in[2];
  const float* Wv   = (const float*)d_in[3];
  const float* Wo   = (const float*)d_in[4];
  const float* Wg1  = (const float*)d_in[5];
  const float* Wg2  = (const float*)d_in[6];
  const float* gamma= (const float*)d_in[7];
  const float* beta = (const float*)d_in[8];
  float* out = (float*)d_out;

  char* ws = (char*)d_ws;
  const size_t MB = 1024*1024;
  float* g2    = (float*)(ws + 0*MB);       // 16MB
  float* attnb = (float*)(ws + 16*MB);      // 16MB
  short* xh    = (short*)(ws + 32*MB);      // 8MB; reused as yh later
  short* xl    = (short*)(ws + 40*MB);      // 8MB; reused as yl later
  short* vh    = (short*)(ws + 48*MB);      // 8MB
  short* vl    = (short*)(ws + 56*MB);      // 8MB
  short* qhb   = (short*)(ws + 64*MB);      // 8MB
  short* qlb   = (short*)(ws + 72*MB);      // 8MB
  short* khb   = (short*)(ws + 80*MB);      // 8MB
  short* klb   = (short*)(ws + 88*MB);      // 8MB
  short* g1h   = (short*)(ws + 96*MB);      // 512KB (dead after g2 gemm)
  short* g1l   = (short*)(ws + 96*MB + 512*1024);  // 512KB
  float* kv    = (float*)(ws + 96*MB);      // 16MB, overwrites g1 AFTER g2 gemm reads it
  short* wqkvh = (short*)(ws + 112*MB);     // 6.25MB  [3200][1024]
  short* wqkvl = (short*)(ws + 119*MB);     // 6.25MB
  short* woh   = (short*)(ws + 126*MB);     // 2MB
  short* wol   = (short*)(ws + 128*MB);     // 2MB
  short* wg2h  = (short*)(ws + 130*MB);                 // 128KB [1024][64]
  short* wg2l  = (short*)(ws + 130*MB + 128*1024);      // 128KB
  float* ct    = (float*)(ws + 130*MB + 256*1024);      // 256KB
  float* st    = (float*)(ws + 130*MB + 512*1024);      // 256KB -> ends 130.75MB
  short* yh    = xh;     // xh dead after QKV gemm
  short* yl    = xl;

  dim3 blk(256);
  sincos_kernel<<<dim3(N_*HALF_/256), blk, 0, stream>>>(ct, st);
  xsplit_kernel<<<dim3(BN*E_/4/256), blk, 0, stream>>>(x, xh, xl);
  wsplit_kernel<<<dim3(16,16), blk, 0, stream>>>(Wq, wqkvh,             wqkvl,             E_, E_);
  wsplit_kernel<<<dim3(16,16), blk, 0, stream>>>(Wk, wqkvh + 1024*1024, wqkvl + 1024*1024, E_, E_);
  wsplit_kernel<<<dim3(16,16), blk, 0, stream>>>(Wv, wqkvh + 2048*1024, wqkvl + 2048*1024, E_, E_);
  wsplit_kernel<<<dim3(16,1),  blk, 0, stream>>>(Wg1, wqkvh + 3072*1024, wqkvl + 3072*1024, E_, D_);
  zfill_kernel<<<dim3(64), blk, 0, stream>>>(wqkvh + 3136*1024, wqkvl + 3136*1024);
  wsplit_kernel<<<dim3(16,16), blk, 0, stream>>>(Wo, woh, wol, E_, E_);
  wsplit_kernel<<<dim3(1,16),  blk, 0, stream>>>(Wg2, wg2h, wg2l, D_, E_);

  // fused QKV+g1 GEMM (N=3200): silu+rope+split for q,k; split for v,g1 — all in epilogue
  gemm_mfma<3><<<dim3(BN/128, NQKV/128), blk, 0, stream>>>(
      xh, xl, wqkvh, wqkvl, nullptr,
      qhb, qlb, khb, klb, vh, vl, g1h, g1l, ct, st, BN, NQKV, E_);
  // g2 = g1 @ Wg2 (fp32 out)
  gemm_mfma<0><<<dim3(BN/128, E_/128), blk, 0, stream>>>(
      g1h, g1l, wg2h, wg2l, g2,
      nullptr,nullptr,nullptr,nullptr,nullptr,nullptr,nullptr,nullptr,
      nullptr, nullptr, BN, E_, D_);
  chunk_kv_kernel<<<dim3(B_*H_*NC), blk, 0, stream>>>(khb, klb, vh, vl, kv);
  kv_scan_kernel<<<dim3(B_*H_*16), blk, 0, stream>>>(kv);
  attn_mfma_kernel<<<dim3(B_*H_*NC), blk, 0, stream>>>(qhb, qlb, khb, klb, vh, vl, kv, attnb);
  gate_ln_kernel<<<dim3(BN), blk, 0, stream>>>(attnb, g2, gamma, beta, yh, yl);
  gemm_mfma<0><<<dim3(BN/128, E_/128), blk, 0, stream>>>(
      yh, yl, woh, wol, out,
      nullptr,nullptr,nullptr,nullptr,nullptr,nullptr,nullptr,nullptr,
      nullptr, nullptr, BN, E_, E_);
}